// Round 13
// baseline (343.122 us; speedup 1.0000x reference)
//
#include <hip/hip_runtime.h>
#include <hip/hip_fp16.h>
#include <math.h>

// Decomposition:
//   t1 = lrelu(feat@W1+b1) (in-wave inside k_A)
//   A = t1 @ Wc + bc  (Wc=W2@Wnm_top: h only feeds A)
//   a_s = A@m; bd[v] = feat[v]@qb (fused into k_A)
//   w_e = exp(lrelu(a_s[src] + c1*bit + bd[dst] + c0, 0.2))  (fp32; no max)
//   neigh[v] = (sum w_e*A[src] + (sum w_e*bit)*wbit)/sum_w + B[v] + b_nm
//   out = mlp_out(relu(neigh))
// R6: fp16 A gather. R13: MFMA for dense matvecs.
// R21: 2-pass binned CSR (runs L2-merge) replaced random-scatter fill.
// R24-R26: persistent k_agg -> phantom E*64B writes, BANNED.
// R28: per-edge random global atomics = poison, BANNED.
// R29/R30: 1-LDS-atomic rank sort + GSZ=32 fixed-stride buckets.
// R31 FAILED (float4 stg 2x bank conflicts; direct-Wnm epilogue reloads).
// R32: R30 k_agg restored + memset fold. 285.9us; k_agg 94.5us = accepted
//   latency floor for this structure. Mid-tier is now ~191us of the total.
// R33: mid-tier only, k_agg/k_Ac untouched:
//   (a) k_p1 re-geometry: EPB 8192->1024 (196->1563 blocks; was 0.77
//       blocks/CU = GPU 3/4 idle), 256 thr, single hist array reused as
//       count->absolute-base (scatter atomicAdd returns final slot),
//       LDS 26.6->13.3KB -> 8 blk/CU, one residency round.
//   (b) k_hp pre-converts Wo1 -> fp16 transposed (Wo1h, 16 spare blocks);
//       k_out stages via pure h8 copies (half bytes, no cvt), grid 512.

typedef _Float16 h2f __attribute__((ext_vector_type(2)));
typedef _Float16 h8  __attribute__((ext_vector_type(8)));
typedef float    f4  __attribute__((ext_vector_type(4)));

#define GSZ_SHIFT 5
#define GSZ 32
#define NBMAX 3328
#define EPB_P1 1024
#define CAPF 768          // fixed bucket stride (mean 512, +11 sigma)

static __device__ __forceinline__ float lrelu(float x, float s) {
    return x >= 0.f ? x : s * x;
}

// ---------- k_hp: blk0 -> sc; blk1..33 -> Wc,bc; blk34..49 -> Wo1h;
//            blk50.. -> zero bcur ----------
// sc[0]=c1=wbit@m  sc[1]=c0=b_nm@m  sc[2+k]=qb[k]=Wnm[129+k]@m
__global__ void __launch_bounds__(256) k_hp(const float* __restrict__ W2,
                                            const float* __restrict__ b2,
                                            const float* __restrict__ Wnm,
                                            const float* __restrict__ b_nm,
                                            const float* __restrict__ attn,
                                            const float* __restrict__ Wo1,
                                            __half* __restrict__ Wc,
                                            float* __restrict__ bc,
                                            float* __restrict__ sc,
                                            __half* __restrict__ Wo1h,
                                            int* __restrict__ bcur, int NB) {
    int t = threadIdx.x;
    if (blockIdx.x == 0) {
        __shared__ float red[128];
        float m = (t < 128) ? attn[t] : 0.f;
        if (t < 128) red[t] = Wnm[128 * 128 + t] * m;
        __syncthreads();
        for (int s = 64; s > 0; s >>= 1) { if (t < s) red[t] += red[t + s]; __syncthreads(); }
        if (t == 0) sc[0] = red[0];
        __syncthreads();
        if (t < 128) red[t] = b_nm[t] * m;
        __syncthreads();
        for (int s = 64; s > 0; s >>= 1) { if (t < s) red[t] += red[t + s]; __syncthreads(); }
        if (t == 0) sc[1] = red[0];
        __syncthreads();
        for (int k = 0; k < 16; k++) {
            if (t < 128) red[t] = Wnm[(129 + k) * 128 + t] * m;
            __syncthreads();
            for (int s = 64; s > 0; s >>= 1) { if (t < s) red[t] += red[t + s]; __syncthreads(); }
            if (t == 0) sc[2 + k] = red[0];
            __syncthreads();
        }
    } else if (blockIdx.x <= 33) {
        int idx = (blockIdx.x - 1) * 256 + t;   // 65*128 outputs (row 64 = bias)
        if (idx >= 65 * 128) return;
        int j = idx >> 7, c = idx & 127;
        const float* row = (j < 64) ? &W2[j * 128] : b2;
        float acc = 0.f;
        for (int cp = 0; cp < 128; cp++) acc = fmaf(row[cp], Wnm[cp * 128 + c], acc);
        if (j < 64) Wc[j * 128 + c] = __float2half_rn(acc);
        else bc[c] = acc;
    } else if (blockIdx.x <= 49) {
        // Wo1h[c*128 + k] = (half)Wo1[k*128 + c]  (transposed, fp16)
        int base = (blockIdx.x - 34) * 1024 + t * 4;
#pragma unroll
        for (int j = 0; j < 4; j++) {
            int idx = base + j;
            int c = idx >> 7, k = idx & 127;
            Wo1h[idx] = __float2half_rn(Wo1[k * 128 + c]);
        }
    } else {
        int i = (blockIdx.x - 50) * 256 + t;
        if (i < NB) bcur[i] = 0;
    }
}

// ---------- k_Ac: fused k_A (t1 -> A -> Ah/a_s/bd), pure MFMA tier ----------
__global__ void __launch_bounds__(256) k_Ac(const float* __restrict__ feat,
                                            const float* __restrict__ W1,
                                            const float* __restrict__ b1,
                                            const float* __restrict__ sc,
                                            const __half* __restrict__ Wc,
                                            const float* __restrict__ bc,
                                            const float* __restrict__ attn,
                                            __half* __restrict__ Ah,
                                            float* __restrict__ a_s,
                                            float* __restrict__ bd,
                                            int n, int ntiles, int gridA) {
    __shared__ __half Wt[128 * 72];       // Wc^T: Wt[c][k], stride 72
    __shared__ float  W1s[16 * 64];
    __shared__ float  b1s[64];
    __shared__ __half t1s[4][16 * 72];
    int t = threadIdx.x;
    int bid = blockIdx.x;
    for (int idx = t; idx < 64 * 128; idx += 256) {
        int k = idx >> 7, c = idx & 127;
        Wt[c * 72 + k] = Wc[idx];
    }
    for (int idx = t; idx < 1024; idx += 256) W1s[idx] = W1[idx];
    if (t < 64) b1s[t] = b1[t];
    __syncthreads();
    int wave = t >> 6, lane = t & 63;
    int c = lane & 15, q = lane >> 4;
    float attv[8], bcv[8];
#pragma unroll
    for (int ct = 0; ct < 8; ct++) {
        attv[ct] = attn[ct * 16 + c];
        bcv[ct]  = bc[ct * 16 + c];
    }
    float qb[16];
#pragma unroll
    for (int k = 0; k < 16; k++) qb[k] = sc[2 + k];
    __half* myT1 = &t1s[wave][0];
    for (int tile = bid * 4 + wave; tile < ntiles; tile += gridA * 4) {
        int rowbase = tile * 16;
        int rm = min(rowbase + c, n - 1);
        const float4* fr = (const float4*)(feat + (size_t)rm * 16);
        float fv[16];
        *(float4*)&fv[0]  = fr[0];
        *(float4*)&fv[4]  = fr[1];
        *(float4*)&fv[8]  = fr[2];
        *(float4*)&fv[12] = fr[3];
        if (q == 0 && rowbase + c < n) {
            float bacc = 0.f;
#pragma unroll
            for (int k = 0; k < 16; k++) bacc = fmaf(fv[k], qb[k], bacc);
            bd[rowbase + c] = bacc;
        }
        {
            _Float16 tv[16];
#pragma unroll
            for (int jj = 0; jj < 16; jj++) {
                int j = q * 16 + jj;
                float acc = b1s[j];
#pragma unroll
                for (int k = 0; k < 16; k++) acc = fmaf(fv[k], W1s[k * 64 + j], acc);
                tv[jj] = (_Float16)lrelu(acc, 0.1f);
            }
            *(h8*)&myT1[c * 72 + q * 16 + 0] = *(h8*)&tv[0];
            *(h8*)&myT1[c * 72 + q * 16 + 8] = *(h8*)&tv[8];
        }
        h8 af[2];
#pragma unroll
        for (int ks = 0; ks < 2; ks++)
            af[ks] = *(const h8*)&myT1[c * 72 + ks * 32 + q * 8];
        f4 acc[8];
#pragma unroll
        for (int ct = 0; ct < 8; ct++) acc[ct] = (f4)(0.f);
#pragma unroll
        for (int ct = 0; ct < 8; ct++) {
#pragma unroll
            for (int ks = 0; ks < 2; ks++) {
                h8 bf = *(const h8*)&Wt[(ct * 16 + c) * 72 + ks * 32 + q * 8];
                acc[ct] = __builtin_amdgcn_mfma_f32_16x16x32_f16(af[ks], bf, acc[ct], 0, 0, 0);
            }
        }
        int rlim = n - rowbase;
        float s0 = 0.f, s1 = 0.f, s2 = 0.f, s3 = 0.f;
#pragma unroll
        for (int ct = 0; ct < 8; ct++) {
            int col = ct * 16 + c;
            float v0 = acc[ct][0] + bcv[ct];
            float v1 = acc[ct][1] + bcv[ct];
            float v2 = acc[ct][2] + bcv[ct];
            float v3 = acc[ct][3] + bcv[ct];
            if (q * 4 + 0 < rlim) Ah[(size_t)(rowbase + q * 4 + 0) * 128 + col] = __float2half_rn(v0);
            if (q * 4 + 1 < rlim) Ah[(size_t)(rowbase + q * 4 + 1) * 128 + col] = __float2half_rn(v1);
            if (q * 4 + 2 < rlim) Ah[(size_t)(rowbase + q * 4 + 2) * 128 + col] = __float2half_rn(v2);
            if (q * 4 + 3 < rlim) Ah[(size_t)(rowbase + q * 4 + 3) * 128 + col] = __float2half_rn(v3);
            s0 = fmaf(v0, attv[ct], s0);
            s1 = fmaf(v1, attv[ct], s1);
            s2 = fmaf(v2, attv[ct], s2);
            s3 = fmaf(v3, attv[ct], s3);
        }
#pragma unroll
        for (int off = 1; off < 16; off <<= 1) {
            s0 += __shfl_xor(s0, off, 64);
            s1 += __shfl_xor(s1, off, 64);
            s2 += __shfl_xor(s2, off, 64);
            s3 += __shfl_xor(s3, off, 64);
        }
        if (c == 0) {
            if (q * 4 + 0 < rlim) a_s[rowbase + q * 4 + 0] = s0;
            if (q * 4 + 1 < rlim) a_s[rowbase + q * 4 + 1] = s1;
            if (q * 4 + 2 < rlim) a_s[rowbase + q * 4 + 2] = s2;
            if (q * 4 + 3 < rlim) a_s[rowbase + q * 4 + 3] = s3;
        }
    }
}

// ---------- pass 1: binned scatter into FIXED-STRIDE bucket runs.
// 256 thr, EPB 1024 -> 1563 blocks (8/CU resident, one round). hist is
// count-phase counts, then rewritten to ABSOLUTE reserved bases, so the
// scatter's atomicAdd(&hist[b],1) returns the final slot directly.
__global__ void __launch_bounds__(256) k_p1(const int* __restrict__ src,
                                            const int* __restrict__ dst,
                                            const float* __restrict__ bit,
                                            const float* __restrict__ a_s,
                                            const float* __restrict__ bd,
                                            const float* __restrict__ sc,
                                            int* __restrict__ bcur,
                                            float4* __restrict__ tmp,
                                            int E, int NB) {
    __shared__ int hist[NBMAX];           // 13.3KB
    int t = threadIdx.x;
    int e0 = blockIdx.x * EPB_P1;
    int e1 = min(e0 + EPB_P1, E);
    for (int i = t; i < NB; i += 256) hist[i] = 0;
    __syncthreads();
    for (int e = e0 + t; e < e1; e += 256)
        atomicAdd(&hist[dst[e] >> GSZ_SHIFT], 1);
    __syncthreads();
    for (int i = t; i < NB; i += 256) {
        int c = hist[i];
        hist[i] = c ? atomicAdd(&bcur[i], c) : 0;   // -> absolute base
    }
    __syncthreads();
    float c1 = sc[0], c0 = sc[1];
    for (int e = e0 + t; e < e1; e += 256) {
        int s = src[e], d = dst[e];
        float bv = bit[e];
        float logit = a_s[s] + c1 * bv + bd[d] + c0;
        float w = __expf(lrelu(logit, 0.2f));
        int b = d >> GSZ_SHIFT;
        int p = atomicAdd(&hist[b], 1);             // absolute slot
        tmp[(size_t)b * CAPF + p] = make_float4(__int_as_float(s), w, w * bv,
                                                __int_as_float(d));
    }
}

// ---------- k_agg: 1-atomic rank sort + per-node gather aggregate ----------
// 1 block = 1 bucket (32 nodes), 256 thr (4 waves), one-shot grid NB.
// LDS ~21KB -> 7 blocks/CU (28 waves). Phases: 3 cond recs in regs;
// rank = atomicAdd(&lcnt[dl],1); wave0 scan -> loff; scatter slot =
// loff[dl]+rank (no atomic); gather 8 nodes/wave (unroll 8), sums in regs.
__global__ void __launch_bounds__(256, 4) k_agg(const float* __restrict__ feat,
                                                const float* __restrict__ Wnm,
                                                const float* __restrict__ b_nm,
                                                const __half* __restrict__ Ah,
                                                const int* __restrict__ bcur,
                                                const float4* __restrict__ tmp,
                                                __half* __restrict__ h_node,
                                                int n, int NB) {
    __shared__ float2 stgA[CAPF];         // 6.1KB {src,w}
    __shared__ float  stgB[CAPF];         // 3.1KB {w*bit}
    __shared__ int   lcnt[GSZ], loffS[GSZ];
    __shared__ float Wq[16 * 128];        // 8KB, Wnm rows 129..144
    __shared__ float wbitL[128], bnmL[128];
    __shared__ float feats[GSZ * 16];     // 2KB
    int t = threadIdx.x;
    int lane = t & 63, wv = t >> 6;       // wv in 0..3
    int b = blockIdx.x;
    int v0 = b << GSZ_SHIFT;
    size_t base = (size_t)b * CAPF;
    int cnt = bcur[b];
    float4 r0, r1, r2;                    // issue record loads first
    bool h0 = t < cnt, h1 = t + 256 < cnt, h2 = t + 512 < cnt;
    if (h0) r0 = tmp[base + t];
    if (h1) r1 = tmp[base + t + 256];
    if (h2) r2 = tmp[base + t + 512];
    for (int i = t; i < 16 * 128; i += 256) Wq[i] = Wnm[129 * 128 + i];
    if (t < 128) { wbitL[t] = Wnm[128 * 128 + t]; bnmL[t] = b_nm[t]; }
    for (int i = t; i < GSZ * 16; i += 256) {
        int v = v0 + (i >> 4);
        feats[i] = (v < n) ? feat[(size_t)v * 16 + (i & 15)] : 0.f;
    }
    if (t < GSZ) lcnt[t] = 0;
    __syncthreads();                      // lcnt zeroed
    int dl0 = 0, dl1 = 0, dl2 = 0, rk0 = 0, rk1 = 0, rk2 = 0;
    if (h0) { dl0 = __float_as_int(r0.w) & (GSZ - 1); rk0 = atomicAdd(&lcnt[dl0], 1); }
    if (h1) { dl1 = __float_as_int(r1.w) & (GSZ - 1); rk1 = atomicAdd(&lcnt[dl1], 1); }
    if (h2) { dl2 = __float_as_int(r2.w) & (GSZ - 1); rk2 = atomicAdd(&lcnt[dl2], 1); }
    __syncthreads();                      // counts complete
    if (wv == 0 && lane < GSZ) {
        int c = lcnt[lane];
        int p = c;
#pragma unroll
        for (int d = 1; d < GSZ; d <<= 1) {
            int y = __shfl_up(p, d, 64);
            if (lane >= d) p += y;
        }
        loffS[lane] = p - c;
    }
    __syncthreads();                      // loff ready
    if (h0) {
        int slot = loffS[dl0] + rk0;
        stgA[slot] = make_float2(r0.x, r0.y); stgB[slot] = r0.z;
    }
    if (h1) {
        int slot = loffS[dl1] + rk1;
        stgA[slot] = make_float2(r1.x, r1.y); stgB[slot] = r1.z;
    }
    if (h2) {
        int slot = loffS[dl2] + rk2;
        stgA[slot] = make_float2(r2.x, r2.y); stgB[slot] = r2.z;
    }
    __syncthreads();                      // stg ready
    float ax[8], ay[8], swr[8], sbr[8];
#pragma unroll
    for (int k = 0; k < 8; k++) {
        int lv = (k << 2) | wv;
        int js = loffS[lv], je = js + lcnt[lv];
        float sx = 0.f, sy = 0.f, sw = 0.f, sb = 0.f;
#pragma unroll 8
        for (int j = js; j < je; j++) {
            float2 rec = stgA[j];
            unsigned sv = (unsigned)__float_as_int(rec.x);
            float2 av = __half22float2(*(const __half2*)&Ah[((size_t)sv << 7) + 2 * lane]);
            sx = fmaf(rec.y, av.x, sx);
            sy = fmaf(rec.y, av.y, sy);
            sw += rec.y;
            sb += stgB[j];
        }
        ax[k] = sx; ay[k] = sy; swr[k] = sw; sbr[k] = sb;
    }
#pragma unroll
    for (int k = 0; k < 8; k++) {
        int lv = (k << 2) | wv;
        int gv = v0 + lv;
        if (gv >= n) continue;
        float swv = swr[k];
        float hx = 0.f, hy = 0.f;
        if (swv > 0.f) {
            float inv = 1.f / swv;
            float sb = sbr[k] * inv;
            float2 bn = *(const float2*)&bnmL[2 * lane];
            float Bx = bn.x, By = bn.y;
#pragma unroll
            for (int kk = 0; kk < 16; kk++) {
                float f = feats[lv * 16 + kk];
                float2 wq = *(const float2*)&Wq[kk * 128 + 2 * lane];
                Bx = fmaf(f, wq.x, Bx);
                By = fmaf(f, wq.y, By);
            }
            float2 wb = *(const float2*)&wbitL[2 * lane];
            hx = fmaf(sb, wb.x, ax[k] * inv) + Bx;
            hy = fmaf(sb, wb.y, ay[k] * inv) + By;
        }
        h2f o; o[0] = (_Float16)fmaxf(hx, 0.f); o[1] = (_Float16)fmaxf(hy, 0.f);
        *(h2f*)&h_node[(size_t)gv * 128 + 2 * lane] = o;
    }
}

// ---------- out = bo2 + sum_c lrelu(h_node@Wo1+bo1,0.1)[c]*Wo2[c], MFMA ----------
__global__ void __launch_bounds__(256) k_out(const __half* __restrict__ h_node,
                                             const __half* __restrict__ Wo1h,
                                             const float* __restrict__ bo1,
                                             const float* __restrict__ Wo2,
                                             const float* __restrict__ bo2,
                                             float* __restrict__ out,
                                             int n, int ntiles) {
    __shared__ __half Wt[128 * 136];
    int t = threadIdx.x;
    for (int i = t; i < 128 * 16; i += 256) {
        int c = i >> 4, s8 = i & 15;
        *(h8*)&Wt[c * 136 + s8 * 8] = *(const h8*)&Wo1h[c * 128 + s8 * 8];
    }
    __syncthreads();
    int wave = t >> 6, lane = t & 63;
    int c = lane & 15, q = lane >> 4;
    float b1v[8], w2v[8];
#pragma unroll
    for (int ct = 0; ct < 8; ct++) {
        b1v[ct] = bo1[ct * 16 + c];
        w2v[ct] = Wo2[ct * 16 + c];
    }
    float bias2 = bo2[0];
    for (int tile = blockIdx.x * 4 + wave; tile < ntiles; tile += gridDim.x * 4) {
        int rowbase = tile * 16;
        int rm = min(rowbase + c, n - 1);
        h8 af[4];
#pragma unroll
        for (int ks = 0; ks < 4; ks++)
            af[ks] = *(const h8*)&h_node[(size_t)rm * 128 + ks * 32 + q * 8];
        f4 acc[8];
#pragma unroll
        for (int ct = 0; ct < 8; ct++) acc[ct] = (f4)(0.f);
#pragma unroll
        for (int ct = 0; ct < 8; ct++) {
#pragma unroll
            for (int ks = 0; ks < 4; ks++) {
                h8 bf = *(const h8*)&Wt[(ct * 16 + c) * 136 + ks * 32 + q * 8];
                acc[ct] = __builtin_amdgcn_mfma_f32_16x16x32_f16(af[ks], bf, acc[ct], 0, 0, 0);
            }
        }
        int rlim = n - rowbase;
        float s0 = 0.f, s1 = 0.f, s2 = 0.f, s3 = 0.f;
#pragma unroll
        for (int ct = 0; ct < 8; ct++) {
            s0 = fmaf(lrelu(acc[ct][0] + b1v[ct], 0.1f), w2v[ct], s0);
            s1 = fmaf(lrelu(acc[ct][1] + b1v[ct], 0.1f), w2v[ct], s1);
            s2 = fmaf(lrelu(acc[ct][2] + b1v[ct], 0.1f), w2v[ct], s2);
            s3 = fmaf(lrelu(acc[ct][3] + b1v[ct], 0.1f), w2v[ct], s3);
        }
#pragma unroll
        for (int off = 1; off < 16; off <<= 1) {
            s0 += __shfl_xor(s0, off, 64);
            s1 += __shfl_xor(s1, off, 64);
            s2 += __shfl_xor(s2, off, 64);
            s3 += __shfl_xor(s3, off, 64);
        }
        if (c == 0) {
            if (q * 4 + 0 < rlim) out[rowbase + q * 4 + 0] = bias2 + s0;
            if (q * 4 + 1 < rlim) out[rowbase + q * 4 + 1] = bias2 + s1;
            if (q * 4 + 2 < rlim) out[rowbase + q * 4 + 2] = bias2 + s2;
            if (q * 4 + 3 < rlim) out[rowbase + q * 4 + 3] = bias2 + s3;
        }
    }
}

extern "C" void kernel_launch(void* const* d_in, const int* in_sizes, int n_in,
                              void* d_out, int out_size, void* d_ws, size_t ws_size,
                              hipStream_t stream) {
    const float* feat = (const float*)d_in[0];
    const float* bit  = (const float*)d_in[1];
    const int*   src  = (const int*)d_in[2];
    const int*   dst  = (const int*)d_in[3];
    const float* W1   = (const float*)d_in[4];
    const float* b1   = (const float*)d_in[5];
    const float* W2   = (const float*)d_in[6];
    const float* b2   = (const float*)d_in[7];
    const float* Wnm  = (const float*)d_in[8];
    const float* bnm  = (const float*)d_in[9];
    const float* attn = (const float*)d_in[10];
    const float* Wo1  = (const float*)d_in[11];
    const float* bo1  = (const float*)d_in[12];
    const float* Wo2  = (const float*)d_in[13];
    const float* bo2  = (const float*)d_in[14];
    float* out = (float*)d_out;
    int n = in_sizes[0] / 16;
    int E = in_sizes[2];
    int ntiles = (n + 15) / 16;
    int NB = (n + GSZ - 1) >> GSZ_SHIFT;

    char* wsp = (char*)d_ws;
    size_t off = 0;
    auto alloc = [&](size_t bytes) -> void* {
        void* p = wsp + off;
        off = (off + bytes + 255) & ~(size_t)255;
        return p;
    };
    __half* Ah       = (__half*)alloc((size_t)n * 128 * 2);
    __half* h_node   = (__half*)alloc((size_t)n * 128 * 2);
    float*  a_s      = (float*)alloc((size_t)n * 4);
    float*  bd       = (float*)alloc((size_t)n * 4);
    int*    bcur     = (int*)alloc((size_t)NBMAX * 4);
    float*  sc       = (float*)alloc(256);
    __half* Wc       = (__half*)alloc(64 * 128 * 2);
    float*  bc       = (float*)alloc(128 * 4);
    __half* Wo1h     = (__half*)alloc(128 * 128 * 2);
    float4* tmp      = (float4*)alloc((size_t)NB * CAPF * 16);

    int gridP1 = (E + EPB_P1 - 1) / EPB_P1;
    int gridA  = 1024;
    int gridHp = 50 + (NB + 255) / 256;

    k_hp<<<gridHp, 256, 0, stream>>>(W2, b2, Wnm, bnm, attn, Wo1, Wc, bc, sc,
                                     Wo1h, bcur, NB);
    k_Ac<<<gridA, 256, 0, stream>>>(feat, W1, b1, sc, Wc, bc, attn,
                                    Ah, a_s, bd, n, ntiles, gridA);
    k_p1<<<gridP1, 256, 0, stream>>>(src, dst, bit, a_s, bd, sc, bcur, tmp, E, NB);
    k_agg<<<NB, 256, 0, stream>>>(feat, Wnm, bnm, Ah, bcur, tmp, h_node, n, NB);
    k_out<<<512, 256, 0, stream>>>(h_node, Wo1h, bo1, Wo2, bo2, out, n, ntiles);
}

// Round 14
// 297.591 us; speedup vs baseline: 1.1530x; 1.1530x over previous
//
#include <hip/hip_runtime.h>
#include <hip/hip_fp16.h>
#include <math.h>

// Decomposition:
//   t1 = lrelu(feat@W1+b1) (in-wave inside k_A)
//   A = t1 @ Wc + bc  (Wc=W2@Wnm_top: h only feeds A)
//   a_s = A@m; bd[v] = feat[v]@qb (fused into k_A)
//   w_e = exp(lrelu(a_s[src] + c1*bit + bd[dst] + c0, 0.2))  (fp32; no max)
//   neigh[v] = (sum w_e*A[src] + (sum w_e*bit)*wbit)/sum_w + B[v] + b_nm
//   out = mlp_out(relu(neigh))
// R6: fp16 A gather. R13: MFMA for dense matvecs.
// R21: 2-pass binned CSR (runs L2-merge) replaced random-scatter fill.
// R24-R26: persistent k_agg -> phantom E*64B writes, BANNED.
// R28: per-edge random global atomics = poison, BANNED.
// R29/R30: 1-LDS-atomic rank sort + GSZ=32 fixed-stride buckets.
// R32: 285.9us; k_agg 94.5us = accepted latency floor.
// R33: k_p1 EPB 8192->1024 FAILED (135us, WRITE 71MB): run-length per
//   (block,bucket) = EPB/NB fell to ~1.2 records -> no L2 write-merge
//   (back to random-64B-line pathology) + 1.4M reserve atomics on 3125
//   addrs. RULE: protect run-length; fewer, fatter binning blocks win.
// R34: k_p1 reverted to R32 (512 thr, EPB 8192, hist+rbase). Kept R33's
//   Wo1h pre-conversion (k_hp blk34..49) + h8-staged k_out at grid 512.

typedef _Float16 h2f __attribute__((ext_vector_type(2)));
typedef _Float16 h8  __attribute__((ext_vector_type(8)));
typedef float    f4  __attribute__((ext_vector_type(4)));

#define GSZ_SHIFT 5
#define GSZ 32
#define NBMAX 3328
#define EPB_P1 8192
#define CAPF 768          // fixed bucket stride (mean 512, +11 sigma)

static __device__ __forceinline__ float lrelu(float x, float s) {
    return x >= 0.f ? x : s * x;
}

// ---------- k_hp: blk0 -> sc; blk1..33 -> Wc,bc; blk34..49 -> Wo1h;
//            blk50.. -> zero bcur ----------
// sc[0]=c1=wbit@m  sc[1]=c0=b_nm@m  sc[2+k]=qb[k]=Wnm[129+k]@m
__global__ void __launch_bounds__(256) k_hp(const float* __restrict__ W2,
                                            const float* __restrict__ b2,
                                            const float* __restrict__ Wnm,
                                            const float* __restrict__ b_nm,
                                            const float* __restrict__ attn,
                                            const float* __restrict__ Wo1,
                                            __half* __restrict__ Wc,
                                            float* __restrict__ bc,
                                            float* __restrict__ sc,
                                            __half* __restrict__ Wo1h,
                                            int* __restrict__ bcur, int NB) {
    int t = threadIdx.x;
    if (blockIdx.x == 0) {
        __shared__ float red[128];
        float m = (t < 128) ? attn[t] : 0.f;
        if (t < 128) red[t] = Wnm[128 * 128 + t] * m;
        __syncthreads();
        for (int s = 64; s > 0; s >>= 1) { if (t < s) red[t] += red[t + s]; __syncthreads(); }
        if (t == 0) sc[0] = red[0];
        __syncthreads();
        if (t < 128) red[t] = b_nm[t] * m;
        __syncthreads();
        for (int s = 64; s > 0; s >>= 1) { if (t < s) red[t] += red[t + s]; __syncthreads(); }
        if (t == 0) sc[1] = red[0];
        __syncthreads();
        for (int k = 0; k < 16; k++) {
            if (t < 128) red[t] = Wnm[(129 + k) * 128 + t] * m;
            __syncthreads();
            for (int s = 64; s > 0; s >>= 1) { if (t < s) red[t] += red[t + s]; __syncthreads(); }
            if (t == 0) sc[2 + k] = red[0];
            __syncthreads();
        }
    } else if (blockIdx.x <= 33) {
        int idx = (blockIdx.x - 1) * 256 + t;   // 65*128 outputs (row 64 = bias)
        if (idx >= 65 * 128) return;
        int j = idx >> 7, c = idx & 127;
        const float* row = (j < 64) ? &W2[j * 128] : b2;
        float acc = 0.f;
        for (int cp = 0; cp < 128; cp++) acc = fmaf(row[cp], Wnm[cp * 128 + c], acc);
        if (j < 64) Wc[j * 128 + c] = __float2half_rn(acc);
        else bc[c] = acc;
    } else if (blockIdx.x <= 49) {
        // Wo1h[c*128 + k] = (half)Wo1[k*128 + c]  (transposed, fp16)
        int base = (blockIdx.x - 34) * 1024 + t * 4;
#pragma unroll
        for (int j = 0; j < 4; j++) {
            int idx = base + j;
            int c = idx >> 7, k = idx & 127;
            Wo1h[idx] = __float2half_rn(Wo1[k * 128 + c]);
        }
    } else {
        int i = (blockIdx.x - 50) * 256 + t;
        if (i < NB) bcur[i] = 0;
    }
}

// ---------- k_Ac: fused k_A (t1 -> A -> Ah/a_s/bd), pure MFMA tier ----------
__global__ void __launch_bounds__(256) k_Ac(const float* __restrict__ feat,
                                            const float* __restrict__ W1,
                                            const float* __restrict__ b1,
                                            const float* __restrict__ sc,
                                            const __half* __restrict__ Wc,
                                            const float* __restrict__ bc,
                                            const float* __restrict__ attn,
                                            __half* __restrict__ Ah,
                                            float* __restrict__ a_s,
                                            float* __restrict__ bd,
                                            int n, int ntiles, int gridA) {
    __shared__ __half Wt[128 * 72];       // Wc^T: Wt[c][k], stride 72
    __shared__ float  W1s[16 * 64];
    __shared__ float  b1s[64];
    __shared__ __half t1s[4][16 * 72];
    int t = threadIdx.x;
    int bid = blockIdx.x;
    for (int idx = t; idx < 64 * 128; idx += 256) {
        int k = idx >> 7, c = idx & 127;
        Wt[c * 72 + k] = Wc[idx];
    }
    for (int idx = t; idx < 1024; idx += 256) W1s[idx] = W1[idx];
    if (t < 64) b1s[t] = b1[t];
    __syncthreads();
    int wave = t >> 6, lane = t & 63;
    int c = lane & 15, q = lane >> 4;
    float attv[8], bcv[8];
#pragma unroll
    for (int ct = 0; ct < 8; ct++) {
        attv[ct] = attn[ct * 16 + c];
        bcv[ct]  = bc[ct * 16 + c];
    }
    float qb[16];
#pragma unroll
    for (int k = 0; k < 16; k++) qb[k] = sc[2 + k];
    __half* myT1 = &t1s[wave][0];
    for (int tile = bid * 4 + wave; tile < ntiles; tile += gridA * 4) {
        int rowbase = tile * 16;
        int rm = min(rowbase + c, n - 1);
        const float4* fr = (const float4*)(feat + (size_t)rm * 16);
        float fv[16];
        *(float4*)&fv[0]  = fr[0];
        *(float4*)&fv[4]  = fr[1];
        *(float4*)&fv[8]  = fr[2];
        *(float4*)&fv[12] = fr[3];
        if (q == 0 && rowbase + c < n) {
            float bacc = 0.f;
#pragma unroll
            for (int k = 0; k < 16; k++) bacc = fmaf(fv[k], qb[k], bacc);
            bd[rowbase + c] = bacc;
        }
        {
            _Float16 tv[16];
#pragma unroll
            for (int jj = 0; jj < 16; jj++) {
                int j = q * 16 + jj;
                float acc = b1s[j];
#pragma unroll
                for (int k = 0; k < 16; k++) acc = fmaf(fv[k], W1s[k * 64 + j], acc);
                tv[jj] = (_Float16)lrelu(acc, 0.1f);
            }
            *(h8*)&myT1[c * 72 + q * 16 + 0] = *(h8*)&tv[0];
            *(h8*)&myT1[c * 72 + q * 16 + 8] = *(h8*)&tv[8];
        }
        h8 af[2];
#pragma unroll
        for (int ks = 0; ks < 2; ks++)
            af[ks] = *(const h8*)&myT1[c * 72 + ks * 32 + q * 8];
        f4 acc[8];
#pragma unroll
        for (int ct = 0; ct < 8; ct++) acc[ct] = (f4)(0.f);
#pragma unroll
        for (int ct = 0; ct < 8; ct++) {
#pragma unroll
            for (int ks = 0; ks < 2; ks++) {
                h8 bf = *(const h8*)&Wt[(ct * 16 + c) * 72 + ks * 32 + q * 8];
                acc[ct] = __builtin_amdgcn_mfma_f32_16x16x32_f16(af[ks], bf, acc[ct], 0, 0, 0);
            }
        }
        int rlim = n - rowbase;
        float s0 = 0.f, s1 = 0.f, s2 = 0.f, s3 = 0.f;
#pragma unroll
        for (int ct = 0; ct < 8; ct++) {
            int col = ct * 16 + c;
            float v0 = acc[ct][0] + bcv[ct];
            float v1 = acc[ct][1] + bcv[ct];
            float v2 = acc[ct][2] + bcv[ct];
            float v3 = acc[ct][3] + bcv[ct];
            if (q * 4 + 0 < rlim) Ah[(size_t)(rowbase + q * 4 + 0) * 128 + col] = __float2half_rn(v0);
            if (q * 4 + 1 < rlim) Ah[(size_t)(rowbase + q * 4 + 1) * 128 + col] = __float2half_rn(v1);
            if (q * 4 + 2 < rlim) Ah[(size_t)(rowbase + q * 4 + 2) * 128 + col] = __float2half_rn(v2);
            if (q * 4 + 3 < rlim) Ah[(size_t)(rowbase + q * 4 + 3) * 128 + col] = __float2half_rn(v3);
            s0 = fmaf(v0, attv[ct], s0);
            s1 = fmaf(v1, attv[ct], s1);
            s2 = fmaf(v2, attv[ct], s2);
            s3 = fmaf(v3, attv[ct], s3);
        }
#pragma unroll
        for (int off = 1; off < 16; off <<= 1) {
            s0 += __shfl_xor(s0, off, 64);
            s1 += __shfl_xor(s1, off, 64);
            s2 += __shfl_xor(s2, off, 64);
            s3 += __shfl_xor(s3, off, 64);
        }
        if (c == 0) {
            if (q * 4 + 0 < rlim) a_s[rowbase + q * 4 + 0] = s0;
            if (q * 4 + 1 < rlim) a_s[rowbase + q * 4 + 1] = s1;
            if (q * 4 + 2 < rlim) a_s[rowbase + q * 4 + 2] = s2;
            if (q * 4 + 3 < rlim) a_s[rowbase + q * 4 + 3] = s3;
        }
    }
}

// ---------- pass 1: binned scatter into FIXED-STRIDE bucket runs (R32 form).
// 512 thr, EPB 8192 -> run-length EPB/NB ~ 2.6 recs/bucket keeps L2
// write-merge alive; 196 blocks x ~2600 reserve atomics only.
__global__ void __launch_bounds__(512) k_p1(const int* __restrict__ src,
                                            const int* __restrict__ dst,
                                            const float* __restrict__ bit,
                                            const float* __restrict__ a_s,
                                            const float* __restrict__ bd,
                                            const float* __restrict__ sc,
                                            int* __restrict__ bcur,
                                            float4* __restrict__ tmp,
                                            int E, int NB) {
    __shared__ int hist[NBMAX];
    __shared__ int rbase[NBMAX];
    int t = threadIdx.x;
    int e0 = blockIdx.x * EPB_P1;
    int e1 = min(e0 + EPB_P1, E);
    for (int i = t; i < NB; i += 512) hist[i] = 0;
    __syncthreads();
    for (int e = e0 + t; e < e1; e += 512)
        atomicAdd(&hist[dst[e] >> GSZ_SHIFT], 1);
    __syncthreads();
    for (int i = t; i < NB; i += 512) {
        int c = hist[i];
        rbase[i] = c ? atomicAdd(&bcur[i], c) : 0;
        hist[i] = 0;
    }
    __syncthreads();
    float c1 = sc[0], c0 = sc[1];
    for (int e = e0 + t; e < e1; e += 512) {
        int s = src[e], d = dst[e];
        float bv = bit[e];
        float logit = a_s[s] + c1 * bv + bd[d] + c0;
        float w = __expf(lrelu(logit, 0.2f));
        int b = d >> GSZ_SHIFT;
        int p = rbase[b] + atomicAdd(&hist[b], 1);
        tmp[(size_t)b * CAPF + p] = make_float4(__int_as_float(s), w, w * bv,
                                                __int_as_float(d));
    }
}

// ---------- k_agg: 1-atomic rank sort + per-node gather aggregate ----------
// 1 block = 1 bucket (32 nodes), 256 thr (4 waves), one-shot grid NB.
// LDS ~21KB -> 7 blocks/CU (28 waves). Phases: 3 cond recs in regs;
// rank = atomicAdd(&lcnt[dl],1); wave0 scan -> loff; scatter slot =
// loff[dl]+rank (no atomic); gather 8 nodes/wave (unroll 8), sums in regs.
__global__ void __launch_bounds__(256, 4) k_agg(const float* __restrict__ feat,
                                                const float* __restrict__ Wnm,
                                                const float* __restrict__ b_nm,
                                                const __half* __restrict__ Ah,
                                                const int* __restrict__ bcur,
                                                const float4* __restrict__ tmp,
                                                __half* __restrict__ h_node,
                                                int n, int NB) {
    __shared__ float2 stgA[CAPF];         // 6.1KB {src,w}
    __shared__ float  stgB[CAPF];         // 3.1KB {w*bit}
    __shared__ int   lcnt[GSZ], loffS[GSZ];
    __shared__ float Wq[16 * 128];        // 8KB, Wnm rows 129..144
    __shared__ float wbitL[128], bnmL[128];
    __shared__ float feats[GSZ * 16];     // 2KB
    int t = threadIdx.x;
    int lane = t & 63, wv = t >> 6;       // wv in 0..3
    int b = blockIdx.x;
    int v0 = b << GSZ_SHIFT;
    size_t base = (size_t)b * CAPF;
    int cnt = bcur[b];
    float4 r0, r1, r2;                    // issue record loads first
    bool h0 = t < cnt, h1 = t + 256 < cnt, h2 = t + 512 < cnt;
    if (h0) r0 = tmp[base + t];
    if (h1) r1 = tmp[base + t + 256];
    if (h2) r2 = tmp[base + t + 512];
    for (int i = t; i < 16 * 128; i += 256) Wq[i] = Wnm[129 * 128 + i];
    if (t < 128) { wbitL[t] = Wnm[128 * 128 + t]; bnmL[t] = b_nm[t]; }
    for (int i = t; i < GSZ * 16; i += 256) {
        int v = v0 + (i >> 4);
        feats[i] = (v < n) ? feat[(size_t)v * 16 + (i & 15)] : 0.f;
    }
    if (t < GSZ) lcnt[t] = 0;
    __syncthreads();                      // lcnt zeroed
    int dl0 = 0, dl1 = 0, dl2 = 0, rk0 = 0, rk1 = 0, rk2 = 0;
    if (h0) { dl0 = __float_as_int(r0.w) & (GSZ - 1); rk0 = atomicAdd(&lcnt[dl0], 1); }
    if (h1) { dl1 = __float_as_int(r1.w) & (GSZ - 1); rk1 = atomicAdd(&lcnt[dl1], 1); }
    if (h2) { dl2 = __float_as_int(r2.w) & (GSZ - 1); rk2 = atomicAdd(&lcnt[dl2], 1); }
    __syncthreads();                      // counts complete
    if (wv == 0 && lane < GSZ) {
        int c = lcnt[lane];
        int p = c;
#pragma unroll
        for (int d = 1; d < GSZ; d <<= 1) {
            int y = __shfl_up(p, d, 64);
            if (lane >= d) p += y;
        }
        loffS[lane] = p - c;
    }
    __syncthreads();                      // loff ready
    if (h0) {
        int slot = loffS[dl0] + rk0;
        stgA[slot] = make_float2(r0.x, r0.y); stgB[slot] = r0.z;
    }
    if (h1) {
        int slot = loffS[dl1] + rk1;
        stgA[slot] = make_float2(r1.x, r1.y); stgB[slot] = r1.z;
    }
    if (h2) {
        int slot = loffS[dl2] + rk2;
        stgA[slot] = make_float2(r2.x, r2.y); stgB[slot] = r2.z;
    }
    __syncthreads();                      // stg ready
    float ax[8], ay[8], swr[8], sbr[8];
#pragma unroll
    for (int k = 0; k < 8; k++) {
        int lv = (k << 2) | wv;
        int js = loffS[lv], je = js + lcnt[lv];
        float sx = 0.f, sy = 0.f, sw = 0.f, sb = 0.f;
#pragma unroll 8
        for (int j = js; j < je; j++) {
            float2 rec = stgA[j];
            unsigned sv = (unsigned)__float_as_int(rec.x);
            float2 av = __half22float2(*(const __half2*)&Ah[((size_t)sv << 7) + 2 * lane]);
            sx = fmaf(rec.y, av.x, sx);
            sy = fmaf(rec.y, av.y, sy);
            sw += rec.y;
            sb += stgB[j];
        }
        ax[k] = sx; ay[k] = sy; swr[k] = sw; sbr[k] = sb;
    }
#pragma unroll
    for (int k = 0; k < 8; k++) {
        int lv = (k << 2) | wv;
        int gv = v0 + lv;
        if (gv >= n) continue;
        float swv = swr[k];
        float hx = 0.f, hy = 0.f;
        if (swv > 0.f) {
            float inv = 1.f / swv;
            float sb = sbr[k] * inv;
            float2 bn = *(const float2*)&bnmL[2 * lane];
            float Bx = bn.x, By = bn.y;
#pragma unroll
            for (int kk = 0; kk < 16; kk++) {
                float f = feats[lv * 16 + kk];
                float2 wq = *(const float2*)&Wq[kk * 128 + 2 * lane];
                Bx = fmaf(f, wq.x, Bx);
                By = fmaf(f, wq.y, By);
            }
            float2 wb = *(const float2*)&wbitL[2 * lane];
            hx = fmaf(sb, wb.x, ax[k] * inv) + Bx;
            hy = fmaf(sb, wb.y, ay[k] * inv) + By;
        }
        h2f o; o[0] = (_Float16)fmaxf(hx, 0.f); o[1] = (_Float16)fmaxf(hy, 0.f);
        *(h2f*)&h_node[(size_t)gv * 128 + 2 * lane] = o;
    }
}

// ---------- out = bo2 + sum_c lrelu(h_node@Wo1+bo1,0.1)[c]*Wo2[c], MFMA ----------
__global__ void __launch_bounds__(256) k_out(const __half* __restrict__ h_node,
                                             const __half* __restrict__ Wo1h,
                                             const float* __restrict__ bo1,
                                             const float* __restrict__ Wo2,
                                             const float* __restrict__ bo2,
                                             float* __restrict__ out,
                                             int n, int ntiles) {
    __shared__ __half Wt[128 * 136];
    int t = threadIdx.x;
    for (int i = t; i < 128 * 16; i += 256) {
        int c = i >> 4, s8 = i & 15;
        *(h8*)&Wt[c * 136 + s8 * 8] = *(const h8*)&Wo1h[c * 128 + s8 * 8];
    }
    __syncthreads();
    int wave = t >> 6, lane = t & 63;
    int c = lane & 15, q = lane >> 4;
    float b1v[8], w2v[8];
#pragma unroll
    for (int ct = 0; ct < 8; ct++) {
        b1v[ct] = bo1[ct * 16 + c];
        w2v[ct] = Wo2[ct * 16 + c];
    }
    float bias2 = bo2[0];
    for (int tile = blockIdx.x * 4 + wave; tile < ntiles; tile += gridDim.x * 4) {
        int rowbase = tile * 16;
        int rm = min(rowbase + c, n - 1);
        h8 af[4];
#pragma unroll
        for (int ks = 0; ks < 4; ks++)
            af[ks] = *(const h8*)&h_node[(size_t)rm * 128 + ks * 32 + q * 8];
        f4 acc[8];
#pragma unroll
        for (int ct = 0; ct < 8; ct++) acc[ct] = (f4)(0.f);
#pragma unroll
        for (int ct = 0; ct < 8; ct++) {
#pragma unroll
            for (int ks = 0; ks < 4; ks++) {
                h8 bf = *(const h8*)&Wt[(ct * 16 + c) * 136 + ks * 32 + q * 8];
                acc[ct] = __builtin_amdgcn_mfma_f32_16x16x32_f16(af[ks], bf, acc[ct], 0, 0, 0);
            }
        }
        int rlim = n - rowbase;
        float s0 = 0.f, s1 = 0.f, s2 = 0.f, s3 = 0.f;
#pragma unroll
        for (int ct = 0; ct < 8; ct++) {
            s0 = fmaf(lrelu(acc[ct][0] + b1v[ct], 0.1f), w2v[ct], s0);
            s1 = fmaf(lrelu(acc[ct][1] + b1v[ct], 0.1f), w2v[ct], s1);
            s2 = fmaf(lrelu(acc[ct][2] + b1v[ct], 0.1f), w2v[ct], s2);
            s3 = fmaf(lrelu(acc[ct][3] + b1v[ct], 0.1f), w2v[ct], s3);
        }
#pragma unroll
        for (int off = 1; off < 16; off <<= 1) {
            s0 += __shfl_xor(s0, off, 64);
            s1 += __shfl_xor(s1, off, 64);
            s2 += __shfl_xor(s2, off, 64);
            s3 += __shfl_xor(s3, off, 64);
        }
        if (c == 0) {
            if (q * 4 + 0 < rlim) out[rowbase + q * 4 + 0] = bias2 + s0;
            if (q * 4 + 1 < rlim) out[rowbase + q * 4 + 1] = bias2 + s1;
            if (q * 4 + 2 < rlim) out[rowbase + q * 4 + 2] = bias2 + s2;
            if (q * 4 + 3 < rlim) out[rowbase + q * 4 + 3] = bias2 + s3;
        }
    }
}

extern "C" void kernel_launch(void* const* d_in, const int* in_sizes, int n_in,
                              void* d_out, int out_size, void* d_ws, size_t ws_size,
                              hipStream_t stream) {
    const float* feat = (const float*)d_in[0];
    const float* bit  = (const float*)d_in[1];
    const int*   src  = (const int*)d_in[2];
    const int*   dst  = (const int*)d_in[3];
    const float* W1   = (const float*)d_in[4];
    const float* b1   = (const float*)d_in[5];
    const float* W2   = (const float*)d_in[6];
    const float* b2   = (const float*)d_in[7];
    const float* Wnm  = (const float*)d_in[8];
    const float* bnm  = (const float*)d_in[9];
    const float* attn = (const float*)d_in[10];
    const float* Wo1  = (const float*)d_in[11];
    const float* bo1  = (const float*)d_in[12];
    const float* Wo2  = (const float*)d_in[13];
    const float* bo2  = (const float*)d_in[14];
    float* out = (float*)d_out;
    int n = in_sizes[0] / 16;
    int E = in_sizes[2];
    int ntiles = (n + 15) / 16;
    int NB = (n + GSZ - 1) >> GSZ_SHIFT;

    char* wsp = (char*)d_ws;
    size_t off = 0;
    auto alloc = [&](size_t bytes) -> void* {
        void* p = wsp + off;
        off = (off + bytes + 255) & ~(size_t)255;
        return p;
    };
    __half* Ah       = (__half*)alloc((size_t)n * 128 * 2);
    __half* h_node   = (__half*)alloc((size_t)n * 128 * 2);
    float*  a_s      = (float*)alloc((size_t)n * 4);
    float*  bd       = (float*)alloc((size_t)n * 4);
    int*    bcur     = (int*)alloc((size_t)NBMAX * 4);
    float*  sc       = (float*)alloc(256);
    __half* Wc       = (__half*)alloc(64 * 128 * 2);
    float*  bc       = (float*)alloc(128 * 4);
    __half* Wo1h     = (__half*)alloc(128 * 128 * 2);
    float4* tmp      = (float4*)alloc((size_t)NB * CAPF * 16);

    int gridP1 = (E + EPB_P1 - 1) / EPB_P1;
    int gridA  = 1024;
    int gridHp = 50 + (NB + 255) / 256;

    k_hp<<<gridHp, 256, 0, stream>>>(W2, b2, Wnm, bnm, attn, Wo1, Wc, bc, sc,
                                     Wo1h, bcur, NB);
    k_Ac<<<gridA, 256, 0, stream>>>(feat, W1, b1, sc, Wc, bc, attn,
                                    Ah, a_s, bd, n, ntiles, gridA);
    k_p1<<<gridP1, 512, 0, stream>>>(src, dst, bit, a_s, bd, sc, bcur, tmp, E, NB);
    k_agg<<<NB, 256, 0, stream>>>(feat, Wnm, bnm, Ah, bcur, tmp, h_node, n, NB);
    k_out<<<512, 256, 0, stream>>>(h_node, Wo1h, bo1, Wo2, bo2, out, n, ntiles);
}

// Round 15
// 271.670 us; speedup vs baseline: 1.2630x; 1.0954x over previous
//
#include <hip/hip_runtime.h>
#include <hip/hip_fp16.h>
#include <math.h>

// Decomposition:
//   t1 = lrelu(feat@W1+b1) (in-wave inside k_A)
//   A = t1 @ Wc + bc  (Wc=W2@Wnm_top: h only feeds A)
//   a_s = A@m; bd[v] = feat[v]@qb (fused into k_A)
//   w_e = exp(lrelu(a_s[src] + c1*bit + bd[dst] + c0, 0.2))  (fp32; no max)
//   neigh[v] = (sum w_e*A[src] + (sum w_e*bit)*wbit)/sum_w + B[v] + b_nm
//   out = mlp_out(relu(neigh))
// R6: fp16 A gather. R13: MFMA for dense matvecs.
// R21: 2-pass binned CSR (runs L2-merge) replaced random-scatter fill.
// R24-R26: persistent k_agg -> phantom E*64B writes, BANNED.
// R28: per-edge random global atomics = poison, BANNED.
// R29/R30: 1-LDS-atomic rank sort + GSZ=32 fixed-stride buckets.
// R32: 285.9us; k_agg ~92us = accepted latency floor.
// R33: k_p1 EPB shrink FAILED (run-length EPB/NB must stay >= ~2.5).
// R34: 297.6us (+11.7 vs R32) - two unbenched deltas: uncoalesced Wo1h
//   transpose reads in k_hp (stride-512B) + k_out grid 512 (tail).
// R35: recovery round, no new ideas: (a) Wo1h via 32x32 LDS tile
//   transpose (coalesced both sides); (b) k_out grid back to 1024,
//   keeping h8 staging; (c) k_Ac/k_p1/k_agg byte-identical to R32 forms.
//   Pre-committed: if ~285 clean -> declare converged next round.

typedef _Float16 h2f __attribute__((ext_vector_type(2)));
typedef _Float16 h8  __attribute__((ext_vector_type(8)));
typedef float    f4  __attribute__((ext_vector_type(4)));

#define GSZ_SHIFT 5
#define GSZ 32
#define NBMAX 3328
#define EPB_P1 8192
#define CAPF 768          // fixed bucket stride (mean 512, +11 sigma)

static __device__ __forceinline__ float lrelu(float x, float s) {
    return x >= 0.f ? x : s * x;
}

// ---------- k_hp: blk0 -> sc; blk1..33 -> Wc,bc; blk34..49 -> Wo1h
//            (tiled transpose); blk50.. -> zero bcur ----------
// sc[0]=c1=wbit@m  sc[1]=c0=b_nm@m  sc[2+k]=qb[k]=Wnm[129+k]@m
__global__ void __launch_bounds__(256) k_hp(const float* __restrict__ W2,
                                            const float* __restrict__ b2,
                                            const float* __restrict__ Wnm,
                                            const float* __restrict__ b_nm,
                                            const float* __restrict__ attn,
                                            const float* __restrict__ Wo1,
                                            __half* __restrict__ Wc,
                                            float* __restrict__ bc,
                                            float* __restrict__ sc,
                                            __half* __restrict__ Wo1h,
                                            int* __restrict__ bcur, int NB) {
    int t = threadIdx.x;
    if (blockIdx.x == 0) {
        __shared__ float red[128];
        float m = (t < 128) ? attn[t] : 0.f;
        if (t < 128) red[t] = Wnm[128 * 128 + t] * m;
        __syncthreads();
        for (int s = 64; s > 0; s >>= 1) { if (t < s) red[t] += red[t + s]; __syncthreads(); }
        if (t == 0) sc[0] = red[0];
        __syncthreads();
        if (t < 128) red[t] = b_nm[t] * m;
        __syncthreads();
        for (int s = 64; s > 0; s >>= 1) { if (t < s) red[t] += red[t + s]; __syncthreads(); }
        if (t == 0) sc[1] = red[0];
        __syncthreads();
        for (int k = 0; k < 16; k++) {
            if (t < 128) red[t] = Wnm[(129 + k) * 128 + t] * m;
            __syncthreads();
            for (int s = 64; s > 0; s >>= 1) { if (t < s) red[t] += red[t + s]; __syncthreads(); }
            if (t == 0) sc[2 + k] = red[0];
            __syncthreads();
        }
    } else if (blockIdx.x <= 33) {
        int idx = (blockIdx.x - 1) * 256 + t;   // 65*128 outputs (row 64 = bias)
        if (idx >= 65 * 128) return;
        int j = idx >> 7, c = idx & 127;
        const float* row = (j < 64) ? &W2[j * 128] : b2;
        float acc = 0.f;
        for (int cp = 0; cp < 128; cp++) acc = fmaf(row[cp], Wnm[cp * 128 + c], acc);
        if (j < 64) Wc[j * 128 + c] = __float2half_rn(acc);
        else bc[c] = acc;
    } else if (blockIdx.x <= 49) {
        // Wo1h[c*128 + k] = (half)Wo1[k*128 + c] via 32x32 LDS tile.
        __shared__ __half tile[32][33];
        int ti = blockIdx.x - 34;
        int bi = ti >> 2, bj = ti & 3;          // row-tile, col-tile
        int kk4 = (t >> 5) << 2, cc = t & 31;
#pragma unroll
        for (int r = 0; r < 4; r++) {
            int k = bi * 32 + kk4 + r;
            tile[kk4 + r][cc] = __float2half_rn(Wo1[k * 128 + bj * 32 + cc]);
        }
        __syncthreads();
#pragma unroll
        for (int r = 0; r < 4; r++) {
            int c = bj * 32 + kk4 + r;
            Wo1h[c * 128 + bi * 32 + cc] = tile[cc][kk4 + r];
        }
    } else {
        int i = (blockIdx.x - 50) * 256 + t;
        if (i < NB) bcur[i] = 0;
    }
}

// ---------- k_Ac: fused k_A (t1 -> A -> Ah/a_s/bd), pure MFMA tier ----------
__global__ void __launch_bounds__(256) k_Ac(const float* __restrict__ feat,
                                            const float* __restrict__ W1,
                                            const float* __restrict__ b1,
                                            const float* __restrict__ sc,
                                            const __half* __restrict__ Wc,
                                            const float* __restrict__ bc,
                                            const float* __restrict__ attn,
                                            __half* __restrict__ Ah,
                                            float* __restrict__ a_s,
                                            float* __restrict__ bd,
                                            int n, int ntiles, int gridA) {
    __shared__ __half Wt[128 * 72];       // Wc^T: Wt[c][k], stride 72
    __shared__ float  W1s[16 * 64];
    __shared__ float  b1s[64];
    __shared__ __half t1s[4][16 * 72];
    int t = threadIdx.x;
    int bid = blockIdx.x;
    for (int idx = t; idx < 64 * 128; idx += 256) {
        int k = idx >> 7, c = idx & 127;
        Wt[c * 72 + k] = Wc[idx];
    }
    for (int idx = t; idx < 1024; idx += 256) W1s[idx] = W1[idx];
    if (t < 64) b1s[t] = b1[t];
    __syncthreads();
    int wave = t >> 6, lane = t & 63;
    int c = lane & 15, q = lane >> 4;
    float attv[8], bcv[8];
#pragma unroll
    for (int ct = 0; ct < 8; ct++) {
        attv[ct] = attn[ct * 16 + c];
        bcv[ct]  = bc[ct * 16 + c];
    }
    float qb[16];
#pragma unroll
    for (int k = 0; k < 16; k++) qb[k] = sc[2 + k];
    __half* myT1 = &t1s[wave][0];
    for (int tile = bid * 4 + wave; tile < ntiles; tile += gridA * 4) {
        int rowbase = tile * 16;
        int rm = min(rowbase + c, n - 1);
        const float4* fr = (const float4*)(feat + (size_t)rm * 16);
        float fv[16];
        *(float4*)&fv[0]  = fr[0];
        *(float4*)&fv[4]  = fr[1];
        *(float4*)&fv[8]  = fr[2];
        *(float4*)&fv[12] = fr[3];
        if (q == 0 && rowbase + c < n) {
            float bacc = 0.f;
#pragma unroll
            for (int k = 0; k < 16; k++) bacc = fmaf(fv[k], qb[k], bacc);
            bd[rowbase + c] = bacc;
        }
        {
            _Float16 tv[16];
#pragma unroll
            for (int jj = 0; jj < 16; jj++) {
                int j = q * 16 + jj;
                float acc = b1s[j];
#pragma unroll
                for (int k = 0; k < 16; k++) acc = fmaf(fv[k], W1s[k * 64 + j], acc);
                tv[jj] = (_Float16)lrelu(acc, 0.1f);
            }
            *(h8*)&myT1[c * 72 + q * 16 + 0] = *(h8*)&tv[0];
            *(h8*)&myT1[c * 72 + q * 16 + 8] = *(h8*)&tv[8];
        }
        h8 af[2];
#pragma unroll
        for (int ks = 0; ks < 2; ks++)
            af[ks] = *(const h8*)&myT1[c * 72 + ks * 32 + q * 8];
        f4 acc[8];
#pragma unroll
        for (int ct = 0; ct < 8; ct++) acc[ct] = (f4)(0.f);
#pragma unroll
        for (int ct = 0; ct < 8; ct++) {
#pragma unroll
            for (int ks = 0; ks < 2; ks++) {
                h8 bf = *(const h8*)&Wt[(ct * 16 + c) * 72 + ks * 32 + q * 8];
                acc[ct] = __builtin_amdgcn_mfma_f32_16x16x32_f16(af[ks], bf, acc[ct], 0, 0, 0);
            }
        }
        int rlim = n - rowbase;
        float s0 = 0.f, s1 = 0.f, s2 = 0.f, s3 = 0.f;
#pragma unroll
        for (int ct = 0; ct < 8; ct++) {
            int col = ct * 16 + c;
            float v0 = acc[ct][0] + bcv[ct];
            float v1 = acc[ct][1] + bcv[ct];
            float v2 = acc[ct][2] + bcv[ct];
            float v3 = acc[ct][3] + bcv[ct];
            if (q * 4 + 0 < rlim) Ah[(size_t)(rowbase + q * 4 + 0) * 128 + col] = __float2half_rn(v0);
            if (q * 4 + 1 < rlim) Ah[(size_t)(rowbase + q * 4 + 1) * 128 + col] = __float2half_rn(v1);
            if (q * 4 + 2 < rlim) Ah[(size_t)(rowbase + q * 4 + 2) * 128 + col] = __float2half_rn(v2);
            if (q * 4 + 3 < rlim) Ah[(size_t)(rowbase + q * 4 + 3) * 128 + col] = __float2half_rn(v3);
            s0 = fmaf(v0, attv[ct], s0);
            s1 = fmaf(v1, attv[ct], s1);
            s2 = fmaf(v2, attv[ct], s2);
            s3 = fmaf(v3, attv[ct], s3);
        }
#pragma unroll
        for (int off = 1; off < 16; off <<= 1) {
            s0 += __shfl_xor(s0, off, 64);
            s1 += __shfl_xor(s1, off, 64);
            s2 += __shfl_xor(s2, off, 64);
            s3 += __shfl_xor(s3, off, 64);
        }
        if (c == 0) {
            if (q * 4 + 0 < rlim) a_s[rowbase + q * 4 + 0] = s0;
            if (q * 4 + 1 < rlim) a_s[rowbase + q * 4 + 1] = s1;
            if (q * 4 + 2 < rlim) a_s[rowbase + q * 4 + 2] = s2;
            if (q * 4 + 3 < rlim) a_s[rowbase + q * 4 + 3] = s3;
        }
    }
}

// ---------- pass 1: binned scatter into FIXED-STRIDE bucket runs (R32 form).
// 512 thr, EPB 8192 -> run-length EPB/NB ~ 2.6 recs/bucket keeps L2
// write-merge alive; 196 blocks x ~2600 reserve atomics only.
__global__ void __launch_bounds__(512) k_p1(const int* __restrict__ src,
                                            const int* __restrict__ dst,
                                            const float* __restrict__ bit,
                                            const float* __restrict__ a_s,
                                            const float* __restrict__ bd,
                                            const float* __restrict__ sc,
                                            int* __restrict__ bcur,
                                            float4* __restrict__ tmp,
                                            int E, int NB) {
    __shared__ int hist[NBMAX];
    __shared__ int rbase[NBMAX];
    int t = threadIdx.x;
    int e0 = blockIdx.x * EPB_P1;
    int e1 = min(e0 + EPB_P1, E);
    for (int i = t; i < NB; i += 512) hist[i] = 0;
    __syncthreads();
    for (int e = e0 + t; e < e1; e += 512)
        atomicAdd(&hist[dst[e] >> GSZ_SHIFT], 1);
    __syncthreads();
    for (int i = t; i < NB; i += 512) {
        int c = hist[i];
        rbase[i] = c ? atomicAdd(&bcur[i], c) : 0;
        hist[i] = 0;
    }
    __syncthreads();
    float c1 = sc[0], c0 = sc[1];
    for (int e = e0 + t; e < e1; e += 512) {
        int s = src[e], d = dst[e];
        float bv = bit[e];
        float logit = a_s[s] + c1 * bv + bd[d] + c0;
        float w = __expf(lrelu(logit, 0.2f));
        int b = d >> GSZ_SHIFT;
        int p = rbase[b] + atomicAdd(&hist[b], 1);
        tmp[(size_t)b * CAPF + p] = make_float4(__int_as_float(s), w, w * bv,
                                                __int_as_float(d));
    }
}

// ---------- k_agg: 1-atomic rank sort + per-node gather aggregate ----------
// 1 block = 1 bucket (32 nodes), 256 thr (4 waves), one-shot grid NB.
// LDS ~21KB -> 7 blocks/CU (28 waves). Phases: 3 cond recs in regs;
// rank = atomicAdd(&lcnt[dl],1); wave0 scan -> loff; scatter slot =
// loff[dl]+rank (no atomic); gather 8 nodes/wave (unroll 8), sums in regs.
__global__ void __launch_bounds__(256, 4) k_agg(const float* __restrict__ feat,
                                                const float* __restrict__ Wnm,
                                                const float* __restrict__ b_nm,
                                                const __half* __restrict__ Ah,
                                                const int* __restrict__ bcur,
                                                const float4* __restrict__ tmp,
                                                __half* __restrict__ h_node,
                                                int n, int NB) {
    __shared__ float2 stgA[CAPF];         // 6.1KB {src,w}
    __shared__ float  stgB[CAPF];         // 3.1KB {w*bit}
    __shared__ int   lcnt[GSZ], loffS[GSZ];
    __shared__ float Wq[16 * 128];        // 8KB, Wnm rows 129..144
    __shared__ float wbitL[128], bnmL[128];
    __shared__ float feats[GSZ * 16];     // 2KB
    int t = threadIdx.x;
    int lane = t & 63, wv = t >> 6;       // wv in 0..3
    int b = blockIdx.x;
    int v0 = b << GSZ_SHIFT;
    size_t base = (size_t)b * CAPF;
    int cnt = bcur[b];
    float4 r0, r1, r2;                    // issue record loads first
    bool h0 = t < cnt, h1 = t + 256 < cnt, h2 = t + 512 < cnt;
    if (h0) r0 = tmp[base + t];
    if (h1) r1 = tmp[base + t + 256];
    if (h2) r2 = tmp[base + t + 512];
    for (int i = t; i < 16 * 128; i += 256) Wq[i] = Wnm[129 * 128 + i];
    if (t < 128) { wbitL[t] = Wnm[128 * 128 + t]; bnmL[t] = b_nm[t]; }
    for (int i = t; i < GSZ * 16; i += 256) {
        int v = v0 + (i >> 4);
        feats[i] = (v < n) ? feat[(size_t)v * 16 + (i & 15)] : 0.f;
    }
    if (t < GSZ) lcnt[t] = 0;
    __syncthreads();                      // lcnt zeroed
    int dl0 = 0, dl1 = 0, dl2 = 0, rk0 = 0, rk1 = 0, rk2 = 0;
    if (h0) { dl0 = __float_as_int(r0.w) & (GSZ - 1); rk0 = atomicAdd(&lcnt[dl0], 1); }
    if (h1) { dl1 = __float_as_int(r1.w) & (GSZ - 1); rk1 = atomicAdd(&lcnt[dl1], 1); }
    if (h2) { dl2 = __float_as_int(r2.w) & (GSZ - 1); rk2 = atomicAdd(&lcnt[dl2], 1); }
    __syncthreads();                      // counts complete
    if (wv == 0 && lane < GSZ) {
        int c = lcnt[lane];
        int p = c;
#pragma unroll
        for (int d = 1; d < GSZ; d <<= 1) {
            int y = __shfl_up(p, d, 64);
            if (lane >= d) p += y;
        }
        loffS[lane] = p - c;
    }
    __syncthreads();                      // loff ready
    if (h0) {
        int slot = loffS[dl0] + rk0;
        stgA[slot] = make_float2(r0.x, r0.y); stgB[slot] = r0.z;
    }
    if (h1) {
        int slot = loffS[dl1] + rk1;
        stgA[slot] = make_float2(r1.x, r1.y); stgB[slot] = r1.z;
    }
    if (h2) {
        int slot = loffS[dl2] + rk2;
        stgA[slot] = make_float2(r2.x, r2.y); stgB[slot] = r2.z;
    }
    __syncthreads();                      // stg ready
    float ax[8], ay[8], swr[8], sbr[8];
#pragma unroll
    for (int k = 0; k < 8; k++) {
        int lv = (k << 2) | wv;
        int js = loffS[lv], je = js + lcnt[lv];
        float sx = 0.f, sy = 0.f, sw = 0.f, sb = 0.f;
#pragma unroll 8
        for (int j = js; j < je; j++) {
            float2 rec = stgA[j];
            unsigned sv = (unsigned)__float_as_int(rec.x);
            float2 av = __half22float2(*(const __half2*)&Ah[((size_t)sv << 7) + 2 * lane]);
            sx = fmaf(rec.y, av.x, sx);
            sy = fmaf(rec.y, av.y, sy);
            sw += rec.y;
            sb += stgB[j];
        }
        ax[k] = sx; ay[k] = sy; swr[k] = sw; sbr[k] = sb;
    }
#pragma unroll
    for (int k = 0; k < 8; k++) {
        int lv = (k << 2) | wv;
        int gv = v0 + lv;
        if (gv >= n) continue;
        float swv = swr[k];
        float hx = 0.f, hy = 0.f;
        if (swv > 0.f) {
            float inv = 1.f / swv;
            float sb = sbr[k] * inv;
            float2 bn = *(const float2*)&bnmL[2 * lane];
            float Bx = bn.x, By = bn.y;
#pragma unroll
            for (int kk = 0; kk < 16; kk++) {
                float f = feats[lv * 16 + kk];
                float2 wq = *(const float2*)&Wq[kk * 128 + 2 * lane];
                Bx = fmaf(f, wq.x, Bx);
                By = fmaf(f, wq.y, By);
            }
            float2 wb = *(const float2*)&wbitL[2 * lane];
            hx = fmaf(sb, wb.x, ax[k] * inv) + Bx;
            hy = fmaf(sb, wb.y, ay[k] * inv) + By;
        }
        h2f o; o[0] = (_Float16)fmaxf(hx, 0.f); o[1] = (_Float16)fmaxf(hy, 0.f);
        *(h2f*)&h_node[(size_t)gv * 128 + 2 * lane] = o;
    }
}

// ---------- out = bo2 + sum_c lrelu(h_node@Wo1+bo1,0.1)[c]*Wo2[c], MFMA ----------
__global__ void __launch_bounds__(256) k_out(const __half* __restrict__ h_node,
                                             const __half* __restrict__ Wo1h,
                                             const float* __restrict__ bo1,
                                             const float* __restrict__ Wo2,
                                             const float* __restrict__ bo2,
                                             float* __restrict__ out,
                                             int n, int ntiles) {
    __shared__ __half Wt[128 * 136];
    int t = threadIdx.x;
    for (int i = t; i < 128 * 16; i += 256) {
        int c = i >> 4, s8 = i & 15;
        *(h8*)&Wt[c * 136 + s8 * 8] = *(const h8*)&Wo1h[c * 128 + s8 * 8];
    }
    __syncthreads();
    int wave = t >> 6, lane = t & 63;
    int c = lane & 15, q = lane >> 4;
    float b1v[8], w2v[8];
#pragma unroll
    for (int ct = 0; ct < 8; ct++) {
        b1v[ct] = bo1[ct * 16 + c];
        w2v[ct] = Wo2[ct * 16 + c];
    }
    float bias2 = bo2[0];
    for (int tile = blockIdx.x * 4 + wave; tile < ntiles; tile += gridDim.x * 4) {
        int rowbase = tile * 16;
        int rm = min(rowbase + c, n - 1);
        h8 af[4];
#pragma unroll
        for (int ks = 0; ks < 4; ks++)
            af[ks] = *(const h8*)&h_node[(size_t)rm * 128 + ks * 32 + q * 8];
        f4 acc[8];
#pragma unroll
        for (int ct = 0; ct < 8; ct++) acc[ct] = (f4)(0.f);
#pragma unroll
        for (int ct = 0; ct < 8; ct++) {
#pragma unroll
            for (int ks = 0; ks < 4; ks++) {
                h8 bf = *(const h8*)&Wt[(ct * 16 + c) * 136 + ks * 32 + q * 8];
                acc[ct] = __builtin_amdgcn_mfma_f32_16x16x32_f16(af[ks], bf, acc[ct], 0, 0, 0);
            }
        }
        int rlim = n - rowbase;
        float s0 = 0.f, s1 = 0.f, s2 = 0.f, s3 = 0.f;
#pragma unroll
        for (int ct = 0; ct < 8; ct++) {
            s0 = fmaf(lrelu(acc[ct][0] + b1v[ct], 0.1f), w2v[ct], s0);
            s1 = fmaf(lrelu(acc[ct][1] + b1v[ct], 0.1f), w2v[ct], s1);
            s2 = fmaf(lrelu(acc[ct][2] + b1v[ct], 0.1f), w2v[ct], s2);
            s3 = fmaf(lrelu(acc[ct][3] + b1v[ct], 0.1f), w2v[ct], s3);
        }
#pragma unroll
        for (int off = 1; off < 16; off <<= 1) {
            s0 += __shfl_xor(s0, off, 64);
            s1 += __shfl_xor(s1, off, 64);
            s2 += __shfl_xor(s2, off, 64);
            s3 += __shfl_xor(s3, off, 64);
        }
        if (c == 0) {
            if (q * 4 + 0 < rlim) out[rowbase + q * 4 + 0] = bias2 + s0;
            if (q * 4 + 1 < rlim) out[rowbase + q * 4 + 1] = bias2 + s1;
            if (q * 4 + 2 < rlim) out[rowbase + q * 4 + 2] = bias2 + s2;
            if (q * 4 + 3 < rlim) out[rowbase + q * 4 + 3] = bias2 + s3;
        }
    }
}

extern "C" void kernel_launch(void* const* d_in, const int* in_sizes, int n_in,
                              void* d_out, int out_size, void* d_ws, size_t ws_size,
                              hipStream_t stream) {
    const float* feat = (const float*)d_in[0];
    const float* bit  = (const float*)d_in[1];
    const int*   src  = (const int*)d_in[2];
    const int*   dst  = (const int*)d_in[3];
    const float* W1   = (const float*)d_in[4];
    const float* b1   = (const float*)d_in[5];
    const float* W2   = (const float*)d_in[6];
    const float* b2   = (const float*)d_in[7];
    const float* Wnm  = (const float*)d_in[8];
    const float* bnm  = (const float*)d_in[9];
    const float* attn = (const float*)d_in[10];
    const float* Wo1  = (const float*)d_in[11];
    const float* bo1  = (const float*)d_in[12];
    const float* Wo2  = (const float*)d_in[13];
    const float* bo2  = (const float*)d_in[14];
    float* out = (float*)d_out;
    int n = in_sizes[0] / 16;
    int E = in_sizes[2];
    int ntiles = (n + 15) / 16;
    int NB = (n + GSZ - 1) >> GSZ_SHIFT;

    char* wsp = (char*)d_ws;
    size_t off = 0;
    auto alloc = [&](size_t bytes) -> void* {
        void* p = wsp + off;
        off = (off + bytes + 255) & ~(size_t)255;
        return p;
    };
    __half* Ah       = (__half*)alloc((size_t)n * 128 * 2);
    __half* h_node   = (__half*)alloc((size_t)n * 128 * 2);
    float*  a_s      = (float*)alloc((size_t)n * 4);
    float*  bd       = (float*)alloc((size_t)n * 4);
    int*    bcur     = (int*)alloc((size_t)NBMAX * 4);
    float*  sc       = (float*)alloc(256);
    __half* Wc       = (__half*)alloc(64 * 128 * 2);
    float*  bc       = (float*)alloc(128 * 4);
    __half* Wo1h     = (__half*)alloc(128 * 128 * 2);
    float4* tmp      = (float4*)alloc((size_t)NB * CAPF * 16);

    int gridP1 = (E + EPB_P1 - 1) / EPB_P1;
    int gridA  = 1024;
    int gridHp = 50 + (NB + 255) / 256;

    k_hp<<<gridHp, 256, 0, stream>>>(W2, b2, Wnm, bnm, attn, Wo1, Wc, bc, sc,
                                     Wo1h, bcur, NB);
    k_Ac<<<gridA, 256, 0, stream>>>(feat, W1, b1, sc, Wc, bc, attn,
                                    Ah, a_s, bd, n, ntiles, gridA);
    k_p1<<<gridP1, 512, 0, stream>>>(src, dst, bit, a_s, bd, sc, bcur, tmp, E, NB);
    k_agg<<<NB, 256, 0, stream>>>(feat, Wnm, bnm, Ah, bcur, tmp, h_node, n, NB);
    k_out<<<1024, 256, 0, stream>>>(h_node, Wo1h, bo1, Wo2, bo2, out, n, ntiles);
}